// Round 2
// baseline (642.486 us; speedup 1.0000x reference)
//
#include <hip/hip_runtime.h>
#include <math.h>

// Pool: c[16][64][256][256] f32 -> pooled[16M] + eta[67M].
// Sampling must bit-match JAX CPU: threefry2x32 partitionable (bits = y0^y1,
// counter (0,i), key (0,42)), XLA-CPU Cephes log, XLA EmitFastTanh, FMA gemms.

#define NTILES 16777216u
#define NBLOCKS 65536u

__device__ __forceinline__ unsigned rotl32(unsigned x, int r) {
  return (x << r) | (x >> (32 - r));
}

// Threefry-2x32, 20 rounds, key (0, 42), counter (0, i). Returns y0 ^ y1
// (JAX partitionable mode, bit_width=32).
__device__ __forceinline__ unsigned tf_bits(unsigned i) {
  const unsigned k0 = 0u;
  const unsigned k1 = 42u;
  const unsigned k2 = 0x1BD11BDAu ^ 0u ^ 42u;
  unsigned x0 = 0u + k0;   // counter hi word = 0
  unsigned x1 = i + k1;
#define TF_ROUND(r) { x0 += x1; x1 = rotl32(x1, (r)); x1 ^= x0; }
  TF_ROUND(13) TF_ROUND(15) TF_ROUND(26) TF_ROUND(6)
  x0 += k1; x1 += k2 + 1u;
  TF_ROUND(17) TF_ROUND(29) TF_ROUND(16) TF_ROUND(24)
  x0 += k2; x1 += k0 + 2u;
  TF_ROUND(13) TF_ROUND(15) TF_ROUND(26) TF_ROUND(6)
  x0 += k0; x1 += k1 + 3u;
  TF_ROUND(17) TF_ROUND(29) TF_ROUND(16) TF_ROUND(24)
  x0 += k1; x1 += k2 + 4u;
  TF_ROUND(13) TF_ROUND(15) TF_ROUND(26) TF_ROUND(6)
  x0 += k2; x1 += k0 + 5u;
#undef TF_ROUND
  return x0 ^ x1;
}

// XLA CPU vectorized f32 log (llvm_ir_runtime Cephes port, FMA-contracted).
// Valid for normal positive inputs (all we feed it).
__device__ __forceinline__ float xla_logf(float a) {
  unsigned b = __float_as_uint(a);
  int e = (int)(b >> 23) - 126;                     // m in [0.5, 1)
  float m = __uint_as_float((b & 0x007fffffu) | 0x3f000000u);
  bool small = m < 0.70710678118654752440f;         // cephes_SQRTHF
  e -= small ? 1 : 0;
  float m1 = m - 1.0f;                              // exact (Sterbenz)
  m = small ? (m1 + m) : m1;                        // exact in both arms
  float z = m * m;
  float y = 7.0376836292e-2f;
  y = fmaf(y, m, -1.1514610310e-1f);
  y = fmaf(y, m,  1.1676998740e-1f);
  y = fmaf(y, m, -1.2420140846e-1f);
  y = fmaf(y, m,  1.4249322787e-1f);
  y = fmaf(y, m, -1.6668057665e-1f);
  y = fmaf(y, m,  2.0000714765e-1f);
  y = fmaf(y, m, -2.4999993993e-1f);
  y = fmaf(y, m,  3.3333331174e-1f);
  y = y * m;                                        // (poly*x)
  y = y * z;                                        // *x^2  (cephes grouping)
  float ef = (float)e;
  y = fmaf(ef, -2.12194440e-4f, y);
  y = fmaf(-0.5f, z, y);
  float r = m + y;
  r = fmaf(ef, 0.693359375f, r);
  return r;
}

// XLA EmitFastTanh (with_fma=true): clamp, rational 7/4 in x^2, small-x -> x.
__device__ __forceinline__ float xla_tanhf(float x) {
  float ax = fabsf(x);
  float xc = fminf(fmaxf(x, -7.99881172180175781f), 7.99881172180175781f);
  float x2 = xc * xc;
  float num = -2.76076847742355e-16f;
  num = fmaf(x2, num,  2.00018790482477e-13f);
  num = fmaf(x2, num, -8.60467152213735e-11f);
  num = fmaf(x2, num,  5.12229709037114e-08f);
  num = fmaf(x2, num,  1.48572235717979e-05f);
  num = fmaf(x2, num,  6.37261928875436e-04f);
  num = fmaf(x2, num,  4.89352455891786e-03f);
  num = xc * num;
  float den = 1.19825839466702e-06f;
  den = fmaf(x2, den, 1.18534705686654e-04f);
  den = fmaf(x2, den, 2.26843463243900e-03f);
  den = fmaf(x2, den, 4.89352518554385e-03f);
  float r = num / den;                              // IEEE divide
  return (ax < 0.0004f) ? x : r;
}

__global__ __launch_bounds__(256) void pool_sample_kernel(
    const float* __restrict__ c,
    const float* __restrict__ w1,
    const float* __restrict__ w2,
    float* __restrict__ pooled,
    float* __restrict__ eta) {
  unsigned t = blockIdx.x * 256u + threadIdx.x;   // tile id
  unsigned j  = t & 127u;
  unsigned i  = (t >> 7) & 127u;
  unsigned bc = t >> 14;

  size_t off = ((size_t)bc * 256u + 2u * i) * 256u + 2u * j;
  float2 r0 = *reinterpret_cast<const float2*>(c + off);
  float2 r1 = *reinterpret_cast<const float2*>(c + off + 256u);
  float t0 = r0.x, t1 = r0.y, t2 = r1.x, t3 = r1.y;

  float a1[16], a2[16];
#pragma unroll
  for (int k = 0; k < 16; ++k) { a1[k] = w1[k]; a2[k] = w2[k]; }

  // h = tanh(W1 . tile): ascending-K FMA chain (Eigen gemm semantics)
  float h[4];
#pragma unroll
  for (int q = 0; q < 4; ++q) {
    float acc = a1[q * 4 + 0] * t0;
    acc = fmaf(a1[q * 4 + 1], t1, acc);
    acc = fmaf(a1[q * 4 + 2], t2, acc);
    acc = fmaf(a1[q * 4 + 3], t3, acc);
    h[q] = xla_tanhf(acc);
  }

  // logits = W2 . h
  float l[4];
#pragma unroll
  for (int q = 0; q < 4; ++q) {
    float acc = a2[q * 4 + 0] * h[0];
    acc = fmaf(a2[q * 4 + 1], h[1], acc);
    acc = fmaf(a2[q * 4 + 2], h[2], acc);
    acc = fmaf(a2[q * 4 + 3], h[3], acc);
    l[q] = acc;
  }

  // eta = softmax(logits) — loose tolerance, device expf is fine
  float mx = fmaxf(fmaxf(l[0], l[1]), fmaxf(l[2], l[3]));
  float e0 = expf(l[0] - mx);
  float e1 = expf(l[1] - mx);
  float e2 = expf(l[2] - mx);
  float e3 = expf(l[3] - mx);
  float inv = 1.0f / (((e0 + e1) + e2) + e3);

  // gumbel-argmax, first-max tie-break (jnp.argmax)
  unsigned base = 4u * t;
  float best = 0.0f;
  int z = 0;
#pragma unroll
  for (int q = 0; q < 4; ++q) {
    unsigned bits = tf_bits(base + (unsigned)q);
    float f = __uint_as_float((bits >> 9) | 0x3f800000u) - 1.0f;
    float u = (f == 0.0f) ? 1.17549435e-38f : f;    // uniform [tiny, 1)
    float tl = xla_logf(u);
    float g = -xla_logf(-tl);                       // gumbel
    float lq = (q == 0) ? l[0] : (q == 1) ? l[1] : (q == 2) ? l[2] : l[3];
    float v = g + lq;                               // ref order: gumbel + logits
    if (q == 0) { best = v; z = 0; }
    else if (v > best) { best = v; z = q; }
  }

  float pv = t0;
  if (z == 1) pv = t1;
  if (z == 2) pv = t2;
  if (z == 3) pv = t3;

  pooled[t] = pv;
  *reinterpret_cast<float4*>(eta + (size_t)base) =
      make_float4(e0 * inv, e1 * inv, e2 * inv, e3 * inv);
}

extern "C" void kernel_launch(void* const* d_in, const int* in_sizes, int n_in,
                              void* d_out, int out_size, void* d_ws, size_t ws_size,
                              hipStream_t stream) {
  const float* c  = (const float*)d_in[0];
  const float* w1 = (const float*)d_in[1];
  const float* w2 = (const float*)d_in[2];
  float* pooled = (float*)d_out;
  float* eta    = (float*)d_out + (size_t)NTILES;

  pool_sample_kernel<<<dim3(NBLOCKS), dim3(256), 0, stream>>>(c, w1, w2, pooled, eta);
}

// Round 4
// 540.590 us; speedup vs baseline: 1.1885x; 1.1885x over previous
//
#include <hip/hip_runtime.h>
#include <math.h>

// Pool: c[16][64][256][256] f32 -> pooled[16M] + eta[67M]. PASSING baseline (R2):
// bit-exact sampling chain = threefry2x32 partitionable (bits=y0^y1, key (0,42))
// + XLA-CPU Cephes log + XLA FastTanh + ascending-K FMA gemms.
// R4 (= R3 with HIP-correct intrinsics): fast gumbel via v_log_f32 with exact
// Cephes fallback when top-2 margin < EPS; fast softmax (v_exp_f32/v_rcp_f32);
// 2 tiles/thread with float4 loads.

#define NTILES   16777216u
#define NBLOCKS  32768u

__device__ __forceinline__ unsigned rotl32(unsigned x, int r) {
  return (x << r) | (x >> (32 - r));
}

// Threefry-2x32, 20 rounds, key (0,42), counter (0,i). Returns y0^y1. EXACT.
__device__ __forceinline__ unsigned tf_bits(unsigned i) {
  const unsigned k0 = 0u;
  const unsigned k1 = 42u;
  const unsigned k2 = 0x1BD11BDAu ^ 0u ^ 42u;
  unsigned x0 = 0u + k0;
  unsigned x1 = i + k1;
#define TF_ROUND(r) { x0 += x1; x1 = rotl32(x1, (r)); x1 ^= x0; }
  TF_ROUND(13) TF_ROUND(15) TF_ROUND(26) TF_ROUND(6)
  x0 += k1; x1 += k2 + 1u;
  TF_ROUND(17) TF_ROUND(29) TF_ROUND(16) TF_ROUND(24)
  x0 += k2; x1 += k0 + 2u;
  TF_ROUND(13) TF_ROUND(15) TF_ROUND(26) TF_ROUND(6)
  x0 += k0; x1 += k1 + 3u;
  TF_ROUND(17) TF_ROUND(29) TF_ROUND(16) TF_ROUND(24)
  x0 += k1; x1 += k2 + 4u;
  TF_ROUND(13) TF_ROUND(15) TF_ROUND(26) TF_ROUND(6)
  x0 += k2; x1 += k0 + 5u;
#undef TF_ROUND
  return x0 ^ x1;
}

// XLA CPU Cephes f32 log (FMA-contracted). EXACT replica — fallback path only.
__device__ __forceinline__ float xla_logf(float a) {
  unsigned b = __float_as_uint(a);
  int e = (int)(b >> 23) - 126;
  float m = __uint_as_float((b & 0x007fffffu) | 0x3f000000u);
  bool small = m < 0.70710678118654752440f;
  e -= small ? 1 : 0;
  float m1 = m - 1.0f;
  m = small ? (m1 + m) : m1;
  float z = m * m;
  float y = 7.0376836292e-2f;
  y = fmaf(y, m, -1.1514610310e-1f);
  y = fmaf(y, m,  1.1676998740e-1f);
  y = fmaf(y, m, -1.2420140846e-1f);
  y = fmaf(y, m,  1.4249322787e-1f);
  y = fmaf(y, m, -1.6668057665e-1f);
  y = fmaf(y, m,  2.0000714765e-1f);
  y = fmaf(y, m, -2.4999993993e-1f);
  y = fmaf(y, m,  3.3333331174e-1f);
  y = y * m;
  y = y * z;
  float ef = (float)e;
  y = fmaf(ef, -2.12194440e-4f, y);
  y = fmaf(-0.5f, z, y);
  float r = m + y;
  r = fmaf(ef, 0.693359375f, r);
  return r;
}

// XLA EmitFastTanh. EXACT replica — in the exactness chain (feeds logits).
__device__ __forceinline__ float xla_tanhf(float x) {
  float ax = fabsf(x);
  float xc = fminf(fmaxf(x, -7.99881172180175781f), 7.99881172180175781f);
  float x2 = xc * xc;
  float num = -2.76076847742355e-16f;
  num = fmaf(x2, num,  2.00018790482477e-13f);
  num = fmaf(x2, num, -8.60467152213735e-11f);
  num = fmaf(x2, num,  5.12229709037114e-08f);
  num = fmaf(x2, num,  1.48572235717979e-05f);
  num = fmaf(x2, num,  6.37261928875436e-04f);
  num = fmaf(x2, num,  4.89352455891786e-03f);
  num = xc * num;
  float den = 1.19825839466702e-06f;
  den = fmaf(x2, den, 1.18534705686654e-04f);
  den = fmaf(x2, den, 2.26843463243900e-03f);
  den = fmaf(x2, den, 4.89352518554385e-03f);
  float r = num / den;
  return (ax < 0.0004f) ? x : r;
}

// Exact gumbel (Cephes) — fallback only.
__device__ __forceinline__ float exact_gumbel(float u) {
  float tl = xla_logf(u);
  return -xla_logf(-tl);
}

// Fast gumbel via v_log_f32 (<=1 ulp). |err| <= ~3e-6 absolute.
__device__ __forceinline__ float fast_gumbel(float u) {
  float lg = __builtin_amdgcn_logf(u);       // log2(u)
  float tn = lg * -0.69314718f;              // -ln(u) > 0
  return __builtin_amdgcn_logf(tn) * -0.69314718f;
}

#define MARGIN_EPS 2.0e-4f   // ~50x the fast-gumbel error bound

__device__ __forceinline__ void process_tile(
    unsigned t, float t0, float t1, float t2, float t3,
    const float* __restrict__ a1, const float* __restrict__ a2,
    float* __restrict__ pooled, float* __restrict__ eta) {
  // h = tanh(W1 . tile): ascending-K FMA chain. EXACT.
  float h[4];
#pragma unroll
  for (int q = 0; q < 4; ++q) {
    float acc = a1[q * 4 + 0] * t0;
    acc = fmaf(a1[q * 4 + 1], t1, acc);
    acc = fmaf(a1[q * 4 + 2], t2, acc);
    acc = fmaf(a1[q * 4 + 3], t3, acc);
    h[q] = xla_tanhf(acc);
  }
  // logits = W2 . h. EXACT.
  float l[4];
#pragma unroll
  for (int q = 0; q < 4; ++q) {
    float acc = a2[q * 4 + 0] * h[0];
    acc = fmaf(a2[q * 4 + 1], h[1], acc);
    acc = fmaf(a2[q * 4 + 2], h[2], acc);
    acc = fmaf(a2[q * 4 + 3], h[3], acc);
    l[q] = acc;
  }

  // eta = softmax(logits). |l| <= 2 analytically -> no max-subtract needed.
  // v_exp_f32 / v_rcp_f32: ~1e-6 rel error, invisible at the bf16 floor.
  float e0 = __builtin_amdgcn_exp2f(l[0] * 1.442695041f);
  float e1 = __builtin_amdgcn_exp2f(l[1] * 1.442695041f);
  float e2 = __builtin_amdgcn_exp2f(l[2] * 1.442695041f);
  float e3 = __builtin_amdgcn_exp2f(l[3] * 1.442695041f);
  float inv = __builtin_amdgcn_rcpf(((e0 + e1) + e2) + e3);

  // uniforms (EXACT bit prep, shared by fast + fallback paths)
  unsigned base = 4u * t;
  float u[4];
#pragma unroll
  for (int q = 0; q < 4; ++q) {
    unsigned bits = tf_bits(base + (unsigned)q);
    float f = __uint_as_float((bits >> 9) | 0x3f800000u) - 1.0f;
    u[q] = (f == 0.0f) ? 1.17549435e-38f : f;
  }

  // fast gumbel-argmax with top-2 margin tracking
  float best = fast_gumbel(u[0]) + l[0];
  float second = -3.402823466e+38f;
  int z = 0;
#pragma unroll
  for (int q = 1; q < 4; ++q) {
    float v = fast_gumbel(u[q]) + l[q];
    if (v > best) { second = best; best = v; z = q; }
    else if (v > second) { second = v; }
  }

  if (best - second < MARGIN_EPS) {
    // rare exact fallback: EXACT replica of the R2 decision chain
    float vb = exact_gumbel(u[0]) + l[0];
    z = 0;
#pragma unroll
    for (int q = 1; q < 4; ++q) {
      float v = exact_gumbel(u[q]) + l[q];
      if (v > vb) { vb = v; z = q; }
    }
  }

  float pv = t0;
  if (z == 1) pv = t1;
  if (z == 2) pv = t2;
  if (z == 3) pv = t3;

  pooled[t] = pv;
  *reinterpret_cast<float4*>(eta + (size_t)base) =
      make_float4(e0 * inv, e1 * inv, e2 * inv, e3 * inv);
}

__global__ __launch_bounds__(256) void pool_sample_kernel(
    const float* __restrict__ c,
    const float* __restrict__ w1,
    const float* __restrict__ w2,
    float* __restrict__ pooled,
    float* __restrict__ eta) {
  unsigned u = blockIdx.x * 256u + threadIdx.x;   // pair id in [0, 8388608)
  unsigned jj = u & 63u;                          // column-pair
  unsigned i  = (u >> 6) & 127u;                  // tile row
  unsigned bc = u >> 13;                          // b*64 + ch

  float a1[16], a2[16];
#pragma unroll
  for (int k = 0; k < 16; ++k) { a1[k] = w1[k]; a2[k] = w2[k]; }

  // two adjacent tiles share two float4 row loads
  size_t off = ((size_t)bc * 256u + 2u * i) * 256u + 4u * jj;
  float4 rA = *reinterpret_cast<const float4*>(c + off);
  float4 rB = *reinterpret_cast<const float4*>(c + off + 256u);

  unsigned t0 = (bc << 14) | (i << 7) | (jj << 1);
  process_tile(t0,     rA.x, rA.y, rB.x, rB.y, a1, a2, pooled, eta);
  process_tile(t0 + 1, rA.z, rA.w, rB.z, rB.w, a1, a2, pooled, eta);
}

extern "C" void kernel_launch(void* const* d_in, const int* in_sizes, int n_in,
                              void* d_out, int out_size, void* d_ws, size_t ws_size,
                              hipStream_t stream) {
  const float* c  = (const float*)d_in[0];
  const float* w1 = (const float*)d_in[1];
  const float* w2 = (const float*)d_in[2];
  float* pooled = (float*)d_out;
  float* eta    = (float*)d_out + (size_t)NTILES;

  pool_sample_kernel<<<dim3(NBLOCKS), dim3(256), 0, stream>>>(c, w1, w2, pooled, eta);
}